// Round 6
// baseline (591.201 us; speedup 1.0000x reference)
//
#include <hip/hip_runtime.h>
#include <hip/hip_bf16.h>

using bf16x8 = __attribute__((ext_vector_type(8))) __bf16;
using f32x4  = __attribute__((ext_vector_type(4))) float;

constexpr int T_SEQ = 4096;
constexpr int HID_C = 2048;
constexpr int NH    = 16;
constexpr int QKV_N = 6144;

__device__ __forceinline__ float head_slope(int h) {
    // slope[h] = -2^{-(h+1)/2} * (1 - 1/31 + 1e-5)
    return -exp2f(-0.5f * (float)(h + 1)) * 0.967751935483871f;
}

__device__ __forceinline__ ushort f2bfu(float f) {
    __hip_bfloat16 h = __float2bfloat16(f);
    return *(ushort*)&h;
}
__device__ __forceinline__ float bfu2f(ushort u) {
    union { unsigned int i; float f; } x; x.i = ((unsigned int)u) << 16; return x.f;
}

// async global -> LDS, 16 bytes per lane; LDS dest = wave-uniform base + lane*16
__device__ __forceinline__ void async16(const ushort* g, ushort* l) {
    __builtin_amdgcn_global_load_lds((const __attribute__((address_space(1))) void*)g,
                                     (__attribute__((address_space(3))) void*)l, 16, 0, 0);
}

// ---------------- fp32 -> bf16 elementwise convert ----------------
__global__ __launch_bounds__(256) void cvt_bf16(const float* __restrict__ src,
                                                ushort* __restrict__ dst, int n) {
    int i = (blockIdx.x * 256 + threadIdx.x) * 8;
    if (i >= n) return;
    float4 a = *(const float4*)(src + i);
    float4 b = *(const float4*)(src + i + 4);
    ushort4 ua = {f2bfu(a.x), f2bfu(a.y), f2bfu(a.z), f2bfu(a.w)};
    ushort4 ub = {f2bfu(b.x), f2bfu(b.y), f2bfu(b.z), f2bfu(b.w)};
    *(ushort4*)(dst + i) = ua;
    *(ushort4*)(dst + i + 4) = ub;
}

// ------- merged weight transposes: fp32 [2048,C] -> bf16 [C,2048], 64x64 tiles -------
__global__ __launch_bounds__(256) void transpose3(const float* __restrict__ wq,
                                                  const float* __restrict__ wg,
                                                  const float* __restrict__ wd,
                                                  ushort* __restrict__ wq_t,
                                                  ushort* __restrict__ wg_t,
                                                  ushort* __restrict__ wd_t) {
    __shared__ ushort tile[64][68];
    int bx = blockIdx.x;
    const float* src; ushort* dst; int C, tcx;
    if (bx < 96)       { src = wq; dst = wq_t; C = QKV_N; tcx = bx; }
    else if (bx < 128) { src = wg; dst = wg_t; C = HID_C; tcx = bx - 96; }
    else               { src = wd; dst = wd_t; C = HID_C; tcx = bx - 128; }
    int R = HID_C;
    int t = threadIdx.x;
    int tr = blockIdx.y * 64, tc = tcx * 64;
    int r0 = t >> 4;
    int c4 = (t & 15) << 2;
#pragma unroll
    for (int p = 0; p < 4; ++p) {
        int row = r0 + p * 16;
        float4 v = *(const float4*)&src[(size_t)(tr + row) * C + tc + c4];
        tile[row][c4 + 0] = f2bfu(v.x);
        tile[row][c4 + 1] = f2bfu(v.y);
        tile[row][c4 + 2] = f2bfu(v.z);
        tile[row][c4 + 3] = f2bfu(v.w);
    }
    __syncthreads();
#pragma unroll
    for (int p = 0; p < 4; ++p) {
        int orow = r0 + p * 16;
        ushort4 u;
        u.x = tile[c4 + 0][orow];
        u.y = tile[c4 + 1][orow];
        u.z = tile[c4 + 2][orow];
        u.w = tile[c4 + 3][orow];
        *(ushort4*)&dst[(size_t)(tc + orow) * R + tr + c4] = u;
    }
}

// ---------------- rope table: tab[t][fi] = (cos, sin) of pos_t * 10000^(-fi/32) ----------------
__global__ __launch_bounds__(256) void rope_tab(const int* __restrict__ positions,
                                                float2* __restrict__ tab) {
    int i = blockIdx.x * 256 + threadIdx.x;   // i < T*32
    int t = i >> 5, fi = i & 31;
    float inv = expf((float)fi * -0.2878231366f);   // ln(10000)/32
    float freq = (float)positions[t] * inv;
    float sn, cs;
    sincosf(freq, &sn, &cs);
    tab[i] = make_float2(cs, sn);
}

// ---------------- shared BK=64 MFMA GEMM core: acc += A[M,K] * Bt[N,K]^T tile ----------------
__device__ __forceinline__ void gemm_core(const ushort* __restrict__ A,
                                          const ushort* __restrict__ Bt,
                                          int K, int bm, int bn,
                                          ushort* As, ushort* Bs,
                                          f32x4 (&acc)[4][4]) {
    int tid = threadIdx.x;
    int lane = tid & 63, wave = tid >> 6;
    int lane15 = lane & 15, quad = lane >> 4;
    int wr = (wave & 1) * 64, wc = (wave >> 1) * 64;
    // DMA mapping: wave stages rows [wave*32, wave*32+32); lane = r_l*8 + g
    // physical group p of row r holds logical col-group p ^ (r&7)  (XOR swizzle)
    int r_l = lane >> 3;
    int g   = lane & 7;
    int colg = ((g ^ r_l) << 3);
    const ushort* gA = A + (size_t)(bm + wave * 32 + r_l) * K + colg;
    const ushort* gB = Bt + (size_t)(bn + wave * 32 + r_l) * K + colg;
    ushort* lA = As + (wave * 32) * 64;
    ushort* lB = Bs + (wave * 32) * 64;
    int sw = lane15 & 7;
    for (int k0 = 0; k0 < K; k0 += 64) {
#pragma unroll
        for (int d = 0; d < 4; ++d) {
            async16(gA + (size_t)d * 8 * K + k0, lA + d * 8 * 64);
            async16(gB + (size_t)d * 8 * K + k0, lB + d * 8 * 64);
        }
        __syncthreads();
#pragma unroll
        for (int ks = 0; ks < 2; ++ks) {
            bf16x8 af[4], bf[4];
#pragma unroll
            for (int i = 0; i < 4; ++i)
                af[i] = *(const bf16x8*)&As[(wr + i * 16 + lane15) * 64 + (((ks * 4 + quad) ^ sw) << 3)];
#pragma unroll
            for (int j = 0; j < 4; ++j)
                bf[j] = *(const bf16x8*)&Bs[(wc + j * 16 + lane15) * 64 + (((ks * 4 + quad) ^ sw) << 3)];
#pragma unroll
            for (int i = 0; i < 4; ++i)
#pragma unroll
                for (int j = 0; j < 4; ++j)
                    acc[i][j] = __builtin_amdgcn_mfma_f32_16x16x32_bf16(af[i], bf[j], acc[i][j], 0, 0, 0);
        }
        __syncthreads();
    }
}

// ---- fused qkv+gate GEMM with full q/k post-processing in the epilogue ----
// Bcat = [wqkv_t ; wg_t] (8192 x K). Column regions (bn>>11): 0=q, 1=k, 2=v, 3=gate.
// q: RMS + rope + scale -> row-major qkv.   k: RMS + rope -> row-major qkv AND kT.
// v: -> vT only.   gate: sigmoid -> gatebuf.
__global__ __launch_bounds__(256) void gemm_fused(const ushort* __restrict__ A,
                                                  const ushort* __restrict__ Bcat,
                                                  ushort* __restrict__ qkv,
                                                  ushort* __restrict__ gate,
                                                  ushort* __restrict__ kT,
                                                  ushort* __restrict__ vT,
                                                  const float2* __restrict__ tab,
                                                  const float* __restrict__ qw,
                                                  const float* __restrict__ kw, int K) {
    __shared__ ushort trbuf[128 * 136];   // 34816 B; As/Bs staging aliases the front 32 KB
    __shared__ float sred[128][2];
    ushort* As = trbuf;
    ushort* Bs = trbuf + 8192;
    int bm = blockIdx.y * 128, bn = blockIdx.x * 128;
    f32x4 acc[4][4] = {};
    gemm_core(A, Bcat, K, bm, bn, As, Bs, acc);
    int tid = threadIdx.x, lane = tid & 63, wave = tid >> 6;
    int lane15 = lane & 15, quad = lane >> 4;
    int wr = (wave & 1) * 64, wc = (wave >> 1) * 64;
    int region = bn >> 11;

    if (region == 3) {   // gate: sigmoid -> bf16
        int cb = bn - QKV_N;
#pragma unroll
        for (int i = 0; i < 4; ++i)
#pragma unroll
            for (int j = 0; j < 4; ++j) {
                int rbase = bm + wr + i * 16 + quad * 4;
                int col = cb + wc + j * 16 + lane15;
#pragma unroll
                for (int r = 0; r < 4; ++r)
                    gate[(size_t)(rbase + r) * HID_C + col] = f2bfu(1.0f / (1.0f + __expf(-acc[i][j][r])));
            }
        return;
    }

    int h = (bn & 2047) >> 7;
    if (region <= 1) {   // q or k: RMS norm + rope
#pragma unroll
        for (int i = 0; i < 4; ++i)
#pragma unroll
            for (int r = 0; r < 4; ++r) {
                float ss = 0.f;
#pragma unroll
                for (int j = 0; j < 4; ++j) { float v = acc[i][j][r]; ss += v * v; }
                ss += __shfl_xor(ss, 1);
                ss += __shfl_xor(ss, 2);
                ss += __shfl_xor(ss, 4);
                ss += __shfl_xor(ss, 8);
                if (lane15 == 0) sred[wr + i * 16 + quad * 4 + r][wave >> 1] = ss;
            }
        __syncthreads();
        const float* wn = (region == 0) ? qw : kw;
        float qs = (region == 0) ? 0.08838834764831845f : 1.0f;  // 128^-0.5 folded into q
        float wv[4];
#pragma unroll
        for (int j = 0; j < 4; ++j) wv[j] = wn[wc + j * 16 + lane15] * qs;
#pragma unroll
        for (int i = 0; i < 4; ++i)
#pragma unroll
            for (int r = 0; r < 4; ++r) {
                int row = wr + i * 16 + quad * 4 + r;
                float rr = rsqrtf((sred[row][0] + sred[row][1]) * (1.0f / 128.0f) + 1e-6f);
#pragma unroll
                for (int j = 0; j < 4; ++j) acc[i][j][r] *= rr * wv[j];
            }
        if (wc == 0) {   // rope region d<64: pairs (j, j+2), fi = j*16+lane15
#pragma unroll
            for (int i = 0; i < 4; ++i)
#pragma unroll
                for (int r = 0; r < 4; ++r) {
                    int t = bm + wr + i * 16 + quad * 4 + r;
#pragma unroll
                    for (int j = 0; j < 2; ++j) {
                        float2 cs = tab[t * 32 + j * 16 + lane15];
                        float x1 = acc[i][j][r], x2 = acc[i][j + 2][r];
                        acc[i][j][r]     = x1 * cs.x - x2 * cs.y;
                        acc[i][j + 2][r] = x2 * cs.x + x1 * cs.y;
                    }
                }
        }
        // row-major store (q and k are read row-major by chunk_out)
#pragma unroll
        for (int i = 0; i < 4; ++i)
#pragma unroll
            for (int j = 0; j < 4; ++j) {
                int rbase = bm + wr + i * 16 + quad * 4;
                int col = bn + wc + j * 16 + lane15;
#pragma unroll
                for (int r = 0; r < 4; ++r)
                    qkv[(size_t)(rbase + r) * QKV_N + col] = f2bfu(acc[i][j][r]);
            }
    }

    if (region >= 1) {   // k or v: transpose via LDS -> kT / vT [h*128+d][T]
#pragma unroll
        for (int i = 0; i < 4; ++i)
#pragma unroll
            for (int j = 0; j < 4; ++j) {
                int d  = wc + j * 16 + lane15;
                int tl = wr + i * 16 + quad * 4;
                ushort4 u;
                u.x = f2bfu(acc[i][j][0]);
                u.y = f2bfu(acc[i][j][1]);
                u.z = f2bfu(acc[i][j][2]);
                u.w = f2bfu(acc[i][j][3]);
                *(ushort4*)&trbuf[d * 136 + tl] = u;
            }
        __syncthreads();
        ushort* dT = ((region == 1) ? kT : vT) + (size_t)(h * 128) * T_SEQ + bm;
        // copy-out: d = wave*32 + s*4 + quad, t = lane15*8  (full 128 t per d;
        // each quad's 16 lanes write one contiguous 256 B row segment)
#pragma unroll
        for (int s = 0; s < 8; ++s) {
            int d = wave * 32 + s * 4 + quad;
            uint4 v = *(const uint4*)&trbuf[d * 136 + lane15 * 8];
            *(uint4*)&dT[(size_t)d * T_SEQ + lane15 * 8] = v;
        }
    }
}

// ---- dense GEMM: fp32 out ----
__global__ __launch_bounds__(256) void gemm_dense(const ushort* __restrict__ A,
                                                  const ushort* __restrict__ Bt,
                                                  float* __restrict__ Cout, int N, int K) {
    __shared__ ushort As[128 * 64];
    __shared__ ushort Bs[128 * 64];
    int bm = blockIdx.y * 128, bn = blockIdx.x * 128;
    f32x4 acc[4][4] = {};
    gemm_core(A, Bt, K, bm, bn, As, Bs, acc);
    int lane = threadIdx.x & 63, wave = threadIdx.x >> 6;
    int lane15 = lane & 15, quad = lane >> 4;
    int wr = (wave & 1) * 64, wc = (wave >> 1) * 64;
#pragma unroll
    for (int i = 0; i < 4; ++i)
#pragma unroll
        for (int j = 0; j < 4; ++j) {
            int rbase = bm + wr + i * 16 + quad * 4;
            int col = bn + wc + j * 16 + lane15;
#pragma unroll
            for (int r = 0; r < 4; ++r)
                Cout[(size_t)(rbase + r) * N + col] = acc[i][j][r];
        }
}

// ------- per-chunk partial state (transposed): PT[c,h][v][d] = sum_j lam^(127-j) v_j[v] k_j[d] -------
__global__ __launch_bounds__(256) void chunk_partial(const ushort* __restrict__ kT,
                                                     const ushort* __restrict__ vT,
                                                     float* __restrict__ PT) {
    int c = blockIdx.x, h = blockIdx.y;
    float slope = head_slope(h);
    float lam_inv = __expf(-slope);
    int tid = threadIdx.x, lane = tid & 63, wave = tid >> 6;
    int lane15 = lane & 15, quad = lane >> 4;
    int wv = (wave & 1) * 64, wd = (wave >> 1) * 64;
    const ushort* vbase = vT + (size_t)h * 128 * T_SEQ + c * 128;
    const ushort* kbase = kT + (size_t)h * 128 * T_SEQ + c * 128;
    f32x4 acc[4][4] = {};
#pragma unroll
    for (int j0 = 0; j0 < 128; j0 += 32) {
        float w8[8];
        w8[0] = __expf(slope * (float)(127 - (j0 + quad * 8)));
#pragma unroll
        for (int kk = 1; kk < 8; ++kk) w8[kk] = w8[kk - 1] * lam_inv;
        bf16x8 afr[4], bfr[4];
#pragma unroll
        for (int i = 0; i < 4; ++i) {
            bf16x8 v = *(const bf16x8*)&vbase[(size_t)(wv + i * 16 + lane15) * T_SEQ + j0 + quad * 8];
#pragma unroll
            for (int kk = 0; kk < 8; ++kk) afr[i][kk] = (__bf16)((float)v[kk] * w8[kk]);
        }
#pragma unroll
        for (int j = 0; j < 4; ++j)
            bfr[j] = *(const bf16x8*)&kbase[(size_t)(wd + j * 16 + lane15) * T_SEQ + j0 + quad * 8];
#pragma unroll
        for (int i = 0; i < 4; ++i)
#pragma unroll
            for (int j = 0; j < 4; ++j)
                acc[i][j] = __builtin_amdgcn_mfma_f32_16x16x32_bf16(afr[i], bfr[j], acc[i][j], 0, 0, 0);
    }
    float* out = PT + ((size_t)c * 16 + h) * 16384;
#pragma unroll
    for (int i = 0; i < 4; ++i)
#pragma unroll
        for (int j = 0; j < 4; ++j)
#pragma unroll
            for (int r = 0; r < 4; ++r)
                out[(size_t)(wv + i * 16 + quad * 4 + r) * 128 + wd + j * 16 + lane15] = acc[i][j][r];
}

// ------- sequential scan over 32 chunks: PT -> Spb (bf16 prefix states) + Sfin -------
__global__ __launch_bounds__(128) void scan_states(const float* __restrict__ PT,
                                                   const float* __restrict__ S0,
                                                   ushort* __restrict__ Spb,
                                                   float* __restrict__ Sfin) {
    int hv = blockIdx.x;              // h*128 + v
    int d = threadIdx.x;              // k-dim
    int h = hv >> 7, v = hv & 127;
    float lamC = __expf(head_slope(h) * 128.0f);
    float s = S0[(size_t)h * 16384 + d * 128 + v];
#pragma unroll
    for (int c = 0; c < 32; ++c) {
        size_t idx = ((size_t)c * 2048 + hv) * 128 + d;
        Spb[idx] = f2bfu(s);          // state BEFORE chunk c, layout [c][h][v][d]
        s = s * lamC + PT[idx];
    }
    Sfin[(size_t)h * 16384 + d * 128 + v] = s;
}

// ------- per-chunk output: QK^T (masked/decayed) * V + lam^(t+1) * Q * S_prev -------
__global__ __launch_bounds__(256) void chunk_out(const ushort* __restrict__ qkv,
                                                 const ushort* __restrict__ vT,
                                                 const ushort* __restrict__ Spb,
                                                 ushort* __restrict__ o) {
    int c = blockIdx.x, h = blockIdx.y;
    float slope = head_slope(h);
    __shared__ ushort Ps[128 * 136];   // padded: row stride 272B -> conflict-free b128
    int tid = threadIdx.x, lane = tid & 63, wave = tid >> 6;
    int lane15 = lane & 15, quad = lane >> 4;
    int t0 = c * 128;
    int tt0 = wave, tt1 = 7 - wave;    // owned t-tiles (balanced triangular split)
    const ushort* qbase = qkv + (size_t)t0 * QKV_N + h * 128;
    const ushort* kbase = qbase + 2048;

    bf16x8 qf0[4], qf1[4];
#pragma unroll
    for (int ds = 0; ds < 4; ++ds) {
        qf0[ds] = *(const bf16x8*)&qbase[(size_t)(tt0 * 16 + lane15) * QKV_N + ds * 32 + quad * 8];
        qf1[ds] = *(const bf16x8*)&qbase[(size_t)(tt1 * 16 + lane15) * QKV_N + ds * 32 + quad * 8];
    }
    // ---- phase 1: scores ----
    f32x4 s0a[4] = {};
    f32x4 s1a[8] = {};
#pragma unroll
    for (int st = 0; st < 8; ++st) {
        if (st <= tt1) {
            bf16x8 kf[4];
#pragma unroll
            for (int ds = 0; ds < 4; ++ds)
                kf[ds] = *(const bf16x8*)&kbase[(size_t)(st * 16 + lane15) * QKV_N + ds * 32 + quad * 8];
#pragma unroll
            for (int ds = 0; ds < 4; ++ds)
                s1a[st] = __builtin_amdgcn_mfma_f32_16x16x32_bf16(qf1[ds], kf[ds], s1a[st], 0, 0, 0);
            if (st <= tt0) {
#pragma unroll
                for (int ds = 0; ds < 4; ++ds)
                    s0a[st] = __builtin_amdgcn_mfma_f32_16x16x32_bf16(qf0[ds], kf[ds], s0a[st], 0, 0, 0);
            }
        }
    }
    // ---- park masked/decayed scores (zero strip pads odd 16-blocks to 32) ----
    int stmax0 = tt0 + ((tt0 & 1) ? 0 : 1);
    int stmax1 = tt1 + ((tt1 & 1) ? 0 : 1);
#pragma unroll
    for (int st = 0; st < 8; ++st) {
        if (st <= stmax1) {
#pragma unroll
            for (int r = 0; r < 4; ++r) {
                int t = tt1 * 16 + quad * 4 + r;
                int s = st * 16 + lane15;
                float val = 0.f;
                if (st <= tt1) val = (s <= t) ? s1a[st][r] * __expf(slope * (float)(t - s)) : 0.f;
                Ps[t * 136 + s] = f2bfu(val);
            }
        }
    }
#pragma unroll
    for (int st = 0; st < 5; ++st) {
        if (st <= stmax0) {
#pragma unroll
            for (int r = 0; r < 4; ++r) {
                int t = tt0 * 16 + quad * 4 + r;
                int s = st * 16 + lane15;
                float val = 0.f;
                if (st <= tt0) val = (s <= t) ? s0a[st][r] * __expf(slope * (float)(t - s)) : 0.f;
                Ps[t * 136 + s] = f2bfu(val);
            }
        }
    }
    __syncthreads();
    // ---- phase 2: O = P*V + diag(lam^(t+1)) Q*S_prev ----
    f32x4 oa0[8] = {};
    f32x4 oa1[8] = {};
    float lam0 = __expf(slope * (float)(tt0 * 16 + lane15 + 1));
    float lam1 = __expf(slope * (float)(tt1 * 16 + lane15 + 1));
    bf16x8 qs0[4], qs1[4];
#pragma unroll
    for (int ds = 0; ds < 4; ++ds)
#pragma unroll
        for (int kk = 0; kk < 8; ++kk) {
            qs0[ds][kk] = (__bf16)((float)qf0[ds][kk] * lam0);
            qs1[ds][kk] = (__bf16)((float)qf1[ds][kk] * lam1);
        }
    const ushort* spb = Spb + ((size_t)c * 2048 + h * 128) * 128;
#pragma unroll
    for (int vt = 0; vt < 8; ++vt)
#pragma unroll
        for (int ds = 0; ds < 4; ++ds) {
            bf16x8 bfrag = *(const bf16x8*)&spb[(vt * 16 + lane15) * 128 + ds * 32 + quad * 8];
            oa0[vt] = __builtin_amdgcn_mfma_f32_16x16x32_bf16(qs0[ds], bfrag, oa0[vt], 0, 0, 0);
            oa1[vt] = __builtin_amdgcn_mfma_f32_16x16x32_bf16(qs1[ds], bfrag, oa1[vt], 0, 0, 0);
        }
    const ushort* vbase = vT + (size_t)h * 128 * T_SEQ + t0;
    int ns0 = (tt0 + 2) >> 1, ns1 = (tt1 + 2) >> 1;
#pragma unroll
    for (int s32 = 0; s32 < 4; ++s32) {
        if (s32 < ns1) {
            bf16x8 af = *(const bf16x8*)&Ps[(tt1 * 16 + lane15) * 136 + s32 * 32 + quad * 8];
#pragma unroll
            for (int vt = 0; vt < 8; ++vt) {
                bf16x8 bfrag = *(const bf16x8*)&vbase[(size_t)(vt * 16 + lane15) * T_SEQ + s32 * 32 + quad * 8];
                oa1[vt] = __builtin_amdgcn_mfma_f32_16x16x32_bf16(af, bfrag, oa1[vt], 0, 0, 0);
            }
        }
    }
#pragma unroll
    for (int s32 = 0; s32 < 2; ++s32) {
        if (s32 < ns0) {
            bf16x8 af = *(const bf16x8*)&Ps[(tt0 * 16 + lane15) * 136 + s32 * 32 + quad * 8];
#pragma unroll
            for (int vt = 0; vt < 8; ++vt) {
                bf16x8 bfrag = *(const bf16x8*)&vbase[(size_t)(vt * 16 + lane15) * T_SEQ + s32 * 32 + quad * 8];
                oa0[vt] = __builtin_amdgcn_mfma_f32_16x16x32_bf16(af, bfrag, oa0[vt], 0, 0, 0);
            }
        }
    }
    // ---- epilogue (bf16) ----
#pragma unroll
    for (int vt = 0; vt < 8; ++vt)
#pragma unroll
        for (int r = 0; r < 4; ++r) {
            o[(size_t)(t0 + tt0 * 16 + quad * 4 + r) * 2048 + h * 128 + vt * 16 + lane15] = f2bfu(oa0[vt][r]);
            o[(size_t)(t0 + tt1 * 16 + quad * 4 + r) * 2048 + h * 128 + vt * 16 + lane15] = f2bfu(oa1[vt][r]);
        }
}

// ---------------- group RMS-norm * g_norm_w * sigmoid-gate -> bf16 ----------------
__global__ __launch_bounds__(256) void gnorm_gate(const ushort* __restrict__ o,
                                                  const ushort* __restrict__ gate,
                                                  const float* __restrict__ gw,
                                                  ushort* __restrict__ gg) {
    int t = blockIdx.x;
    int tid = threadIdx.x;
    const ushort* op = o + (size_t)t * 2048 + tid * 8;
    bf16x8 xv = *(const bf16x8*)op;
    float x[8];
    float ss = 0.0f;
#pragma unroll
    for (int i = 0; i < 8; ++i) { x[i] = (float)xv[i]; ss += x[i] * x[i]; }
#pragma unroll
    for (int off = 16; off > 0; off >>= 1) ss += __shfl_xor(ss, off);  // 32-thread group = 256 elems
    float r = rsqrtf(ss * (1.0f / 256.0f) + 1e-6f);
    const ushort* gp = gate + (size_t)t * 2048;
#pragma unroll
    for (int i = 0; i < 8; ++i) {
        int j = tid * 8 + i;
        float val = x[i] * r * gw[j] * bfu2f(gp[j]);
        gg[(size_t)t * 2048 + j] = f2bfu(val);
    }
}

extern "C" void kernel_launch(void* const* d_in, const int* in_sizes, int n_in,
                              void* d_out, int out_size, void* d_ws, size_t ws_size,
                              hipStream_t stream) {
    const int* positions   = (const int*)d_in[0];
    const float* hidden    = (const float*)d_in[1];
    const float* S0        = (const float*)d_in[2];
    const float* w_qkv     = (const float*)d_in[3];
    const float* w_g       = (const float*)d_in[4];
    const float* w_dense   = (const float*)d_in[5];
    const float* qw        = (const float*)d_in[6];
    const float* kw        = (const float*)d_in[7];
    const float* gw        = (const float*)d_in[8];

    char* ws = (char*)d_ws;
    ushort* qkv     = (ushort*)ws;                    // bf16 T x 6144            [0, 50331648)
    ushort* wqkv_t  = (ushort*)(ws + 50331648);       // bf16 6144 x 2048 (25.2M) — Bcat rows 0..6143
    ushort* wg_t    = (ushort*)(ws + 75497472);       // bf16 2048 x 2048 (8.4M)  — Bcat rows 6144..8191
    float*  PT      = (float*)(ws + 50331648);        // fp32 32x16x128x128 (33.6M) — aliases both (dead)
    ushort* wd_t    = (ushort*)(ws + 83886080);       // bf16 2048 x 2048 (8.4M)
    ushort* gatebuf = (ushort*)(ws + 92274688);       // bf16 T x 2048 (16.8M)
    ushort* hid_b   = (ushort*)(ws + 109051904);      // bf16 T x 2048 (16.8M)
    ushort* Spb     = (ushort*)(ws + 109051904);      // bf16 32x16x128x128 (16.8M) — aliases hid_b (dead)
    ushort* kT      = (ushort*)(ws + 125829120);      // bf16 16x128x4096 (16.8M)
    ushort* vT      = (ushort*)(ws + 142606336);      // bf16 16x128x4096 (16.8M)  total 159,383,552
    ushort* gg      = (ushort*)ws;                    // aliases qkv (dead by gnorm time)

    float* out  = (float*)d_out;
    float* Sfin = out + (size_t)T_SEQ * HID_C;
    ushort* obuf = (ushort*)d_out;                    // first 16.8M of out-region: bf16 attn scratch
    // rope table lives in the dead upper half of the out-region (overwritten by gemm_dense at the end)
    float2* ropet = (float2*)((char*)d_out + 25165824);   // 1 MB

    cvt_bf16<<<T_SEQ * HID_C / (256 * 8), 256, 0, stream>>>(hidden, hid_b, T_SEQ * HID_C);
    transpose3<<<dim3(160, 32), 256, 0, stream>>>(w_qkv, w_g, w_dense, wqkv_t, wg_t, wd_t);
    rope_tab<<<T_SEQ * 32 / 256, 256, 0, stream>>>(positions, ropet);

    gemm_fused<<<dim3((QKV_N + HID_C) / 128, T_SEQ / 128), 256, 0, stream>>>(
        hid_b, wqkv_t, qkv, gatebuf, kT, vT, ropet, qw, kw, HID_C);

    chunk_partial<<<dim3(32, 16), 256, 0, stream>>>(kT, vT, PT);
    scan_states<<<2048, 128, 0, stream>>>(PT, S0, Spb, Sfin);
    chunk_out<<<dim3(32, 16), 256, 0, stream>>>(qkv, vT, Spb, obuf);
    gnorm_gate<<<T_SEQ, 256, 0, stream>>>(obuf, gatebuf, gw, gg);

    gemm_dense<<<dim3(HID_C / 128, T_SEQ / 128), 256, 0, stream>>>(gg, wd_t, out, HID_C, HID_C);
}